// Round 24
// baseline (80.271 us; speedup 1.0000x reference)
//
#include <hip/hip_runtime.h>

namespace {

constexpr int kB  = 16;    // batches
constexpr int kP  = 8;     // pieces
constexpr int kNT = 512;   // time steps (incl. t=0)
constexpr int kNX = 2048;  // cells
constexpr int kW  = 24;    // steps per super-step
constexpr int kOwn = 16;   // cells owned per wave
constexpr int kNS = 22;    // super-steps: 21*24 + 7 = 511 rows
constexpr int kCpB = 128;  // chunks per batch
constexpr int kSolver = kB * kCpB;        // 2048 blocks, 1 wave each
// region per wave = kOwn + 2*kW = 64 cells = 64 lanes x 1 cell

// d_ws: halo[kNS][kB][kNX] f32-bits, data-as-flag (poisoned 0xFFFFFFFF each
// call; real values are u in [0,1] -> distinguishable). Slot s holds every
// block's owned 16 cells at time 24s, global-cell indexed. Slot 0 is never
// read -> dump target for non-writer lanes' unconditional stores.
constexpr size_t kHaloBytes = (size_t)kNS * kB * kNX * 4;   // ~2.9 MB
constexpr int    kPoison    = -1;                           // 0xFFFFFFFF

// Cross-lane shift by one lane via DPP (VALU; no LDS round-trip).
__device__ __forceinline__ float dpp_shr1(float x) {
    return __builtin_bit_cast(float,
        __builtin_amdgcn_update_dpp(0, __builtin_bit_cast(int, x), 0x138, 0xF, 0xF, true));
}
__device__ __forceinline__ float dpp_shl1(float x) {
    return __builtin_bit_cast(float,
        __builtin_amdgcn_update_dpp(0, __builtin_bit_cast(int, x), 0x130, 0xF, 0xF, true));
}

// m = max(-xL, xR, 0) in ONE VOP3. Godunov flux for f(u)=u(1-u) in x=u-1/2
// space: F = 1/4 - m^2; the 1/4 cancels in the flux difference.
__device__ __forceinline__ float max3n(float xL, float xR) {
    float m;
    asm("v_max3_f32 %0, -%1, %2, 0" : "=v"(m) : "v"(xL), "v"(xR));
    return m;
}

// Agent-scope coherence-point ops (relaxed: no cache maintenance).
__device__ __forceinline__ void mall_store(int* p, float v) {
    (void)__hip_atomic_exchange(p, __builtin_bit_cast(int, v),
                                __ATOMIC_RELAXED, __HIP_MEMORY_SCOPE_AGENT);
}
__device__ __forceinline__ int mall_loadi(const int* p) {
    return __hip_atomic_load(p, __ATOMIC_RELAXED, __HIP_MEMORY_SCOPE_AGENT);
}

__global__ __launch_bounds__(64)
void godunov_fused(const float* __restrict__ xs,   // (B, P+1)
                   const float* __restrict__ ks,   // (B, P)
                   const int*   __restrict__ pm,   // (B, P)
                   const float* __restrict__ dxp,  // (B,)
                   const float* __restrict__ dtp,  // (B,)
                   float* __restrict__ out,        // (B,1,NT,NX) fp32
                   int*   __restrict__ halo)       // [kNS][kB][kNX], poisoned
{
    const int p    = blockIdx.x;
    const int b    = p >> 7;         // batch
    const int k    = p & 127;        // chunk within batch
    const int lane = threadIdx.x;    // 0..63, one wave per block
    const int rs   = k * kOwn - kW;  // region start (may be <0)
    const int gi   = rs + lane;      // this lane's cell

    const float dxv = dxp[0];
    const float lam = dtp[0] / dxv;

    // ---- piecewise-constant IC parameters ----
    int np = 0;
    float bnds[kP];
#pragma unroll
    for (int j = 0; j < kP; ++j) {
        int m = pm[b * kP + j];
        np += m;
        bnds[j] = m ? xs[b * (kP + 1) + j + 1] : __builtin_inff();
    }
    const int cap = np - 1;

    auto icval = [&](int g) -> float {
        float xc = ((float)g + 0.5f) * dxv;
        int idx = 0;
#pragma unroll
        for (int j = 0; j < kP; ++j) idx += (xc >= bnds[j]) ? 1 : 0;
        idx = min(idx, cap);
        return ks[b * kP + idx];
    };

    // Constant ghost values (reference: frozen IC endpoints).
    const float gL = icval(0);
    const float gR = icval(kNX - 1);

    const bool  laneIn  = (gi >= 0) && (gi < kNX);
    const float gvv     = (gi < 0) ? gL : gR;
    const float gxv     = gvv - 0.5f;              // pinned value in x-space
    const bool  edgeBlk = (k < 2) || (k >= kCpB - 2);   // regions touching edge

    // ---- seed at t=0 from IC (state in x = u - 1/2 space) ----
    float x = (laneIn ? icval(gi) : gvv) - 0.5f;

    // Lanes 24..39 own exactly the chunk (cells k*16 .. k*16+15).
    const bool writer = (lane >= 24) && (lane < 40);

    if (writer) {   // row 0 = IC (off the hot loop)
        out[((size_t)b * kNT) * kNX + gi] = x + 0.5f;
    }

    // Unconditional stores: writer lanes walk output rows; the other 48 lanes
    // hit a per-block dump inside never-read slot 0 (collisions harmless).
    char* pstore = writer
        ? (char*)(out + ((size_t)b * kNT + 1) * kNX + gi)
        : (char*)(halo + (size_t)p * kOwn + (lane & 15));
    const size_t incB = writer ? (size_t)kNX * sizeof(float) : 0;

    // Per step: 2 dpp + 2 max3 + 2 mul + 2 fma + 1 add + 1 store + addr.
    // Reassociated update keeps each dpp-dependent flux on a 4-hop chain:
    // dpp -> max3 -> mul -> fma.
    auto step_store = [&]() {
        float xm = dpp_shr1(x);       // x of cell gi-1
        float xp = dpp_shl1(x);       // x of cell gi+1
        float m0 = max3n(xm, x);      // left face
        float m1 = max3n(x, xp);      // right face
        float G0 = m0 * m0;
        float G1 = m1 * m1;
        float t  = __builtin_fmaf( lam, G1, x);
        x        = __builtin_fmaf(-lam, G0, t);
        if (edgeBlk) {   // wave-uniform; skipped by 124/128 blocks
            x = laneIn ? x : gxv;
        }
        *reinterpret_cast<float*>(pstore) = x + 0.5f;
        pstore += incB;
    };

#pragma unroll 1
    for (int s = 0; s < kNS; ++s) {
        // ---- re-seed halo lanes (state at time 24*s), data-as-flag ----
        if (s > 0) {
            const int* slot = halo + ((size_t)s * kB + b) * kNX;
            if (lane < 24) {          // left halo: cells [rs, rs+24)
                if (gi >= 0) {        // else: stays pinned at gL
                    const int* hp = slot + gi;
                    int v;
                    for (int it = 0; it < (1 << 22); ++it) {
                        v = mall_loadi(hp);
                        if (v != kPoison) break;
                        __builtin_amdgcn_s_sleep(1);
                    }
                    x = __builtin_bit_cast(float, v) - 0.5f;
                }
            } else if (lane >= 40) {  // right halo: cells [rs+40, rs+64)
                if (gi < kNX) {       // else: stays pinned at gR
                    const int* hp = slot + gi;
                    int v;
                    for (int it = 0; it < (1 << 22); ++it) {
                        v = mall_loadi(hp);
                        if (v != kPoison) break;
                        __builtin_amdgcn_s_sleep(1);
                    }
                    x = __builtin_bit_cast(float, v) - 0.5f;
                }
            }
            // lanes 24..39 keep their registers (own chunk, still valid)
        }

        // ---- steps: 3 octets of 8 (last superstep: just 7 steps) ----
        if (s < kNS - 1) {
#pragma unroll 1
            for (int g = 0; g < 3; ++g) {
#pragma unroll
                for (int q = 0; q < 8; ++q) step_store();
            }
        } else {
#pragma unroll
            for (int q = 0; q < 7; ++q) step_store();   // rows 505..511
        }

        // ---- publish own cell (time 24*(s+1)): fire-and-forget ----
        if (s < kNS - 1 && writer) {
            int* hp = halo + ((size_t)(s + 1) * kB + b) * kNX + gi;
            mall_store(hp, x + 0.5f);
        }
    }
}

}  // namespace

extern "C" void kernel_launch(void* const* d_in, const int* in_sizes, int n_in,
                              void* d_out, int out_size, void* d_ws, size_t ws_size,
                              hipStream_t stream) {
    const float* xs  = (const float*)d_in[0];
    const float* ks  = (const float*)d_in[1];
    const int*   pm  = (const int*)d_in[2];
    const float* dxv = (const float*)d_in[3];
    const float* dtv = (const float*)d_in[4];
    // d_in[5] = t_coords: only carries the (NT, NX) shape; values unused.
    float* out = (float*)d_out;

    int* halo = (int*)d_ws;

    // Re-poison the halo every call (d_ws is not re-poisoned between replays).
    hipMemsetAsync(halo, 0xFF, kHaloBytes, stream);

    hipLaunchKernelGGL(godunov_fused, dim3(kSolver), dim3(64), 0, stream,
                       xs, ks, pm, dxv, dtv, out, halo);
}

// Round 25
// 46.652 us; speedup vs baseline: 1.7206x; 1.7206x over previous
//
#include <hip/hip_runtime.h>

namespace {

constexpr int kB  = 16;    // batches
constexpr int kP  = 8;     // pieces
constexpr int kNT = 512;   // time steps (incl. t=0)
constexpr int kNX = 2048;  // cells
constexpr int kW  = 48;    // steps per super-step
constexpr int kOwn = 32;   // cells owned per wave
constexpr int kNS = 11;    // super-steps: 10*48 + 31 = 511 rows
constexpr int kCpB = 64;   // chunks per batch
constexpr int kSolver = kB * kCpB;        // 1024 blocks, 1 wave each
// region per wave = kOwn + 2*kW = 128 cells = 64 lanes x 2 cells

// d_ws: halo[kNS][kB][kNX] f32-bits, data-as-flag (poisoned 0xFFFFFFFF each
// call; any real value is u in [0,1] -> distinguishable). Slot s is written
// by every block's owned 32 cells at time 48s (global-cell indexed, so the
// 48-wide halo spanning two producer blocks needs no block arithmetic).
// Slot 0 is never read -> dump target for non-writer lanes.
constexpr size_t kHaloBytes = (size_t)kNS * kB * kNX * 4;   // ~1.4 MB
constexpr int    kPoison    = -1;                           // 0xFFFFFFFF

typedef float v2f __attribute__((ext_vector_type(2)));

// Cross-lane shift by one lane via DPP (VALU; no LDS round-trip).
__device__ __forceinline__ float dpp_shr1(float x) {
    return __builtin_bit_cast(float,
        __builtin_amdgcn_update_dpp(0, __builtin_bit_cast(int, x), 0x138, 0xF, 0xF, true));
}
__device__ __forceinline__ float dpp_shl1(float x) {
    return __builtin_bit_cast(float,
        __builtin_amdgcn_update_dpp(0, __builtin_bit_cast(int, x), 0x130, 0xF, 0xF, true));
}

// m = max(-xL, xR, 0) in ONE VOP3. Godunov flux for f(u)=u(1-u) in x=u-1/2
// space: F = 1/4 - m^2; the 1/4 cancels in the flux difference.
__device__ __forceinline__ float max3n(float xL, float xR) {
    float m;
    asm("v_max3_f32 %0, -%1, %2, 0" : "=v"(m) : "v"(xL), "v"(xR));
    return m;
}

// Agent-scope coherence-point ops (relaxed: no cache maintenance).
__device__ __forceinline__ void mall_store(int* p, float v) {
    (void)__hip_atomic_exchange(p, __builtin_bit_cast(int, v),
                                __ATOMIC_RELAXED, __HIP_MEMORY_SCOPE_AGENT);
}
__device__ __forceinline__ int mall_loadi(const int* p) {
    return __hip_atomic_load(p, __ATOMIC_RELAXED, __HIP_MEMORY_SCOPE_AGENT);
}

__global__ __launch_bounds__(64)
void godunov_fused(const float* __restrict__ xs,   // (B, P+1)
                   const float* __restrict__ ks,   // (B, P)
                   const int*   __restrict__ pm,   // (B, P)
                   const float* __restrict__ dxp,  // (B,)
                   const float* __restrict__ dtp,  // (B,)
                   float* __restrict__ out,        // (B,1,NT,NX) fp32
                   int*   __restrict__ halo)       // [kNS][kB][kNX], poisoned
{
    const int p    = blockIdx.x;
    const int b    = p >> 6;         // batch
    const int k    = p & 63;         // chunk within batch
    const int lane = threadIdx.x;    // 0..63, one wave per block
    const int rs   = k * kOwn - kW;  // region start (may be <0)
    const int gi0  = rs + 2 * lane;  // this lane's first cell

    const float dxv = dxp[0];
    const float lam = dtp[0] / dxv;
    const v2f  h2   = {0.5f, 0.5f};

    // ---- piecewise-constant IC parameters ----
    int np = 0;
    float bnds[kP];
#pragma unroll
    for (int j = 0; j < kP; ++j) {
        int m = pm[b * kP + j];
        np += m;
        bnds[j] = m ? xs[b * (kP + 1) + j + 1] : __builtin_inff();
    }
    const int cap = np - 1;

    auto icval = [&](int gi) -> float {
        float xc = ((float)gi + 0.5f) * dxv;
        int idx = 0;
#pragma unroll
        for (int j = 0; j < kP; ++j) idx += (xc >= bnds[j]) ? 1 : 0;
        idx = min(idx, cap);
        return ks[b * kP + idx];
    };

    // Constant ghost values (reference: frozen IC endpoints).
    const float gL = icval(0);
    const float gR = icval(kNX - 1);

    // Region is 2-aligned; each lane's 2 cells are all-in or all-out of domain.
    const bool  laneIn  = (gi0 >= 0) && (gi0 < kNX);
    const float gvv     = (gi0 < 0) ? gL : gR;
    const float gxv     = gvv - 0.5f;              // pinned value in x-space
    const bool  edgeBlk = (k < 2) || (k >= kCpB - 2);   // regions touching domain edge

    // ---- seed at t=0 from IC (state in x = u - 1/2 space) ----
    float x0 = (laneIn ? icval(gi0)     : gvv) - 0.5f;
    float x1 = (laneIn ? icval(gi0 + 1) : gvv) - 0.5f;

    // Lanes 24..39 own exactly the chunk (cells k*32 .. k*32+31).
    const bool writer = (lane >= 24) && (lane < 40);

    if (writer) {   // row 0 = IC (off the hot loop)
        float* p0 = out + ((size_t)b * kNT) * kNX;
        *reinterpret_cast<float2*>(p0 + gi0) = make_float2(x0 + 0.5f, x1 + 0.5f);
    }

    // Unconditional stores: writer lanes walk output rows; the other 48 lanes
    // hit a per-block dump inside never-read slot 0 (collisions harmless).
    char* pstore = writer
        ? (char*)(out + ((size_t)b * kNT + 1) * kNX + gi0)
        : (char*)(halo + p * kOwn + 2 * (lane & 15));
    const size_t incB = writer ? (size_t)kNX * sizeof(float) : 0;

    // Per step: 2 dpp + 3 max3 + 1 pk_mul + 1 mul + 4 fma + 1 pk_add + store.
    // Reassociated update keeps the DPP-dependent flux LAST: chain is
    // dpp -> max3 -> mul -> fma (4 hops).
    auto step_store = [&]() {
        float xm = dpp_shr1(x1);      // x of cell gi0-1
        float xp = dpp_shl1(x0);      // x of cell gi0+2
        float m0 = max3n(xm, x0);
        float m1 = max3n(x0, x1);
        float m2 = max3n(x1, xp);
        v2f mA = {m0, m1};
        v2f GA = mA * mA;             // v_pk_mul_f32: {G0, G1}
        float G2 = m2 * m2;
        // x0' = x0 + lam*(G1-G0); x1' = x1 + lam*(G2-G1); dpp-dep flux last
        float t0 = __builtin_fmaf( lam, GA.y, x0);
        x0       = __builtin_fmaf(-lam, GA.x, t0);
        float t1 = __builtin_fmaf(-lam, GA.y, x1);
        x1       = __builtin_fmaf( lam, G2,   t1);
        if (edgeBlk) {   // wave-uniform; skipped by 60/64 blocks
            x0 = laneIn ? x0 : gxv;
            x1 = laneIn ? x1 : gxv;
        }
        v2f xv = {x0, x1};
        v2f sv = xv + h2;             // v_pk_add_f32
        *reinterpret_cast<float2*>(pstore) = make_float2(sv.x, sv.y);
        pstore += incB;
    };

#pragma unroll 1
    for (int s = 0; s < kNS; ++s) {
        // ---- re-seed halo lanes (state at time 48*s), data-as-flag ----
        if (s > 0) {
            const int* slot = halo + ((size_t)s * kB + b) * kNX;
            if (lane < 24) {          // left halo: cells [rs, rs+48)
                if (gi0 >= 0) {       // else: stays pinned at gL
                    const int* hp = slot + gi0;
                    int v0, v1;
                    for (int it = 0; it < (1 << 22); ++it) {
                        v0 = mall_loadi(hp); v1 = mall_loadi(hp + 1);
                        if (v0 != kPoison && v1 != kPoison) break;
                        __builtin_amdgcn_s_sleep(1);
                    }
                    x0 = __builtin_bit_cast(float, v0) - 0.5f;
                    x1 = __builtin_bit_cast(float, v1) - 0.5f;
                }
            } else if (lane >= 40) {  // right halo: cells [rs+80, rs+128)
                if (gi0 < kNX) {      // else: stays pinned at gR
                    const int* hp = slot + gi0;
                    int v0, v1;
                    for (int it = 0; it < (1 << 22); ++it) {
                        v0 = mall_loadi(hp); v1 = mall_loadi(hp + 1);
                        if (v0 != kPoison && v1 != kPoison) break;
                        __builtin_amdgcn_s_sleep(1);
                    }
                    x0 = __builtin_bit_cast(float, v0) - 0.5f;
                    x1 = __builtin_bit_cast(float, v1) - 0.5f;
                }
            }
            // lanes 24..39 keep their registers (own chunk, still valid)
        }

        // ---- steps: 6 octets (last superstep: 3 octets + 7) ----
        const int noct = (s == kNS - 1) ? 3 : 6;
#pragma unroll 1
        for (int g = 0; g < noct; ++g) {
#pragma unroll
            for (int q = 0; q < 8; ++q) step_store();
        }
        if (s == kNS - 1) {
#pragma unroll
            for (int q = 0; q < 7; ++q) step_store();   // rows 505..511
        }

        // ---- publish own cells (time 48*(s+1)): fire-and-forget ----
        if (s < kNS - 1 && writer) {
            int* hp = halo + ((size_t)(s + 1) * kB + b) * kNX + gi0;
            mall_store(hp,     x0 + 0.5f);
            mall_store(hp + 1, x1 + 0.5f);
        }
    }
}

}  // namespace

extern "C" void kernel_launch(void* const* d_in, const int* in_sizes, int n_in,
                              void* d_out, int out_size, void* d_ws, size_t ws_size,
                              hipStream_t stream) {
    const float* xs  = (const float*)d_in[0];
    const float* ks  = (const float*)d_in[1];
    const int*   pm  = (const int*)d_in[2];
    const float* dxv = (const float*)d_in[3];
    const float* dtv = (const float*)d_in[4];
    // d_in[5] = t_coords: only carries the (NT, NX) shape; values unused.
    float* out = (float*)d_out;

    int* halo = (int*)d_ws;

    // Re-poison the halo every call (d_ws is not re-poisoned between replays).
    hipMemsetAsync(halo, 0xFF, kHaloBytes, stream);

    hipLaunchKernelGGL(godunov_fused, dim3(kSolver), dim3(64), 0, stream,
                       xs, ks, pm, dxv, dtv, out, halo);
}